// Round 3
// baseline (104.254 us; speedup 1.0000x reference)
//
#include <hip/hip_runtime.h>
#include <cstdint>

typedef _Float16 f16x8 __attribute__((ext_vector_type(8)));
typedef float    f32x4 __attribute__((ext_vector_type(4)));

// ---------------- compile-time DCT matrix + grade filter ----------------
constexpr double kPI  = 3.14159265358979323846264338327950288;
constexpr double kLN2 = 0.69314718055994530941723212145818;
constexpr double cos_poly(double x) {            // |x| <= pi/2, Taylor
    double x2 = x * x, term = 1.0, sum = 1.0;
    for (int n = 1; n <= 13; ++n) { term *= -x2 / double((2 * n - 1) * (2 * n)); sum += term; }
    return sum;
}
constexpr double cos_idx(int a) {                // cos(a*pi/64), a mod 128
    a &= 127;
    if (a <= 32)  return  cos_poly(a * kPI / 64.0);
    if (a <= 64)  return -cos_poly((64 - a) * kPI / 64.0);
    if (a <= 96)  return -cos_poly((a - 64) * kPI / 64.0);
    return cos_poly((128 - a) * kPI / 64.0);
}
constexpr double csqrt(double v) {
    double x = 1.0;
    for (int i = 0; i < 60; ++i) x = 0.5 * (x + v / x);
    return x;
}
// double -> float (exact constexpr cast) -> half bits, RNE, normals only.
constexpr unsigned short d2h(double dv) {
    float f = (float)dv;
    double v = (double)f;
    unsigned short s = 0;
    if (v < 0.0) { s = 0x8000; v = -v; }
    if (v == 0.0) return s;
    int e = 0;
    while (v >= 2.0) { v *= 0.5; ++e; }
    while (v < 1.0)  { v *= 2.0; --e; }
    double m = (v - 1.0) * 1024.0;               // v in [1,2)
    int mi = (int)m;
    double fr = m - (double)mi;
    if (fr > 0.5 || (fr == 0.5 && (mi & 1))) ++mi;
    int ef = e + 15;
    if (mi == 1024) { mi = 0; ++ef; }
    return (unsigned short)(s | (ef << 10) | mi);
}
// D fragments in MFMA lane order, fp16 bits, baked at compile time.
// Frag[tile][lane][j] = D[16*tile + (lane&15)][(lane>>4)*8 + j]
// (this is BOTH the A-frag of D and the B-frag of D^T — same index formula).
struct __align__(16) HTab { unsigned short h[1024]; };
constexpr HTab make_H() {
    HTab t{};
    const double s0 = csqrt(1.0 / 32.0);
    for (int tl = 0; tl < 2; ++tl)
        for (int lane = 0; lane < 64; ++lane) {
            const int m  = 16 * tl + (lane & 15);
            const int k0 = (lane >> 4) * 8;
            const double sc = (m == 0) ? s0 : 0.25;   // sqrt(2/32) == 0.25 exactly
            for (int j = 0; j < 8; ++j)
                t.h[(tl * 64 + lane) * 8 + j] = d2h(sc * cos_idx(((2 * (k0 + j) + 1) * m) & 127));
        }
    return t;
}
struct FTab { float f[64]; };
constexpr FTab make_F() {                        // f(s) = ln2 * sum_g [s in band g] 2^g/n_g
    FTab t{};                                    // ln2 folded in: kernel uses log2
    const int lo[6] = {0, 11, 22, 32, 43, 54};
    const int hi[6] = {10, 21, 32, 42, 53, 62};  // s=32 in bands 2 AND 3 (fp64 boundary = 32.0)
    const int n [6] = {66, 187, 306, 286, 165, 45};
    for (int s = 0; s < 64; ++s) {
        double acc = 0.0, w = 1.0;
        for (int g = 0; g < 6; ++g) { if (s >= lo[g] && s <= hi[g]) acc += w / double(n[g]); w *= 2.0; }
        t.f[s] = (float)(acc * kLN2);
    }
    return t;
}
__device__ constexpr HTab cH = make_H();
__device__ constexpr FTab cF = make_F();

#define NP  15376   // 16 * 961 patches
#define NPC 46128   // NP * 3 (patch, channel) tasks
#define LPB 961     // 31*31 patches per batch image
#define TP  36      // LDS T stride: writes bank (16q+4r+n)%32 = 2-way (free);
                    // b128 reads 16B-aligned, uniform 8-per-bank
#define CPX 2883    // blocks per XCD chunk: 23064 = 8 * 2883 (exact -> bijective)

// NO-WORKSPACE SCHEME (this round's change): the 256 MiB d_ws poison fill
// (42 us @ 80% HBM) brackets every iteration.  Scratch need is only 184 KB,
// and the output buffer has room: per-batch partials (961*3 = 2883 floats)
// fit inside batch b's own o=0 output chunk (3072 floats).  k_grade writes
// grades at out[b*3072 + l*3 + c]; the fused k_selgather (block b) reads
// only its own chunk BEFORE its barrier and overwrites its own 4 chunks
// AFTER — no cross-block hazard, d_ws untouched.

// ---------------- kernel 1: per-(patch,channel) grade via MFMA ----------------
// One wave = one task.  TRANSPOSE TRICK: grade weight F[row+col] is symmetric
// and Z only feeds the grade, so compute Z' = D*P^T*D^T = Z^T instead.
// B-frag of P^T is B[k][n] = P[n][k]  -> each lane reads CONTIGUOUS floats:
// 4 x global_load_dwordx4, perfect 64B coalescing.
// XCD swizzle: bijective chunked remap vb = (bid&7)*CPX + (bid>>3) gives each
// XCD a contiguous band of 5766 tasks = exactly 2 batch-images (L2-resident
// reuse window).  Pure permutation of task->block mapping.
// Layouts (verified prior session):
//   A[m=lane&15][k=quad*8+j], B[k=quad*8+j][n=lane&15], C/D: col=lane&15,
//   row=quad*4+reg.
__global__ __launch_bounds__(128, 4) void k_grade(const float* __restrict__ x,
                                                  float* __restrict__ out) {
    __shared__ __align__(16) float sT[2][32 * TP];
    __shared__ float sF[64];
    const int tid  = threadIdx.x;
    const int wv   = tid >> 6, lane = tid & 63;
    const int quad = lane >> 4, n = lane & 15;
    if (tid < 64) sF[tid] = cF.f[tid];

    const int bid = blockIdx.x;                  // 23064 blocks
    const int vb  = (bid & 7) * CPX + (bid >> 3);
    const int tc   = vb * 2 + wv;                // grid exact: 23064*2 = 46128
    const int task = tc / 3, c = tc - task * 3;
    const int b  = task / LPB, l = task - b * LPB;
    const int ph = l / 31, pw = l - ph * 31;

    // D fragments from compile-time table (L2-hot: same 2 KB for all waves)
    const f16x8* DF = (const f16x8*)cH.h;
    const f16x8 d0 = DF[lane], d1 = DF[64 + lane];

    // load P^T directly in B-operand layout: B[quad*8+j][n] = P[n][quad*8+j]
    // lane (quad,n) reads x[row = ph*16+n (+16)], cols pw*16+quad*8 .. +7
    const float* pp = x + (size_t)(b * 3 + c) * 262144
                        + (size_t)(ph * 16 + n) * 512 + pw * 16 + quad * 8;
    const float4 v0 = *(const float4*)(pp);
    const float4 v1 = *(const float4*)(pp + 4);
    const float4 v2 = *(const float4*)(pp + 16 * 512);
    const float4 v3 = *(const float4*)(pp + 16 * 512 + 4);
    f16x8 p0, p1;
    p0[0]=(_Float16)v0.x; p0[1]=(_Float16)v0.y; p0[2]=(_Float16)v0.z; p0[3]=(_Float16)v0.w;
    p0[4]=(_Float16)v1.x; p0[5]=(_Float16)v1.y; p0[6]=(_Float16)v1.z; p0[7]=(_Float16)v1.w;
    p1[0]=(_Float16)v2.x; p1[1]=(_Float16)v2.y; p1[2]=(_Float16)v2.z; p1[3]=(_Float16)v2.w;
    p1[4]=(_Float16)v3.x; p1[5]=(_Float16)v3.y; p1[6]=(_Float16)v3.z; p1[7]=(_Float16)v3.w;

    // stage 1: T = D * P^T (4 tiles of 16x16, K=32 in one MFMA each)
    const f32x4 z4 = {0.f, 0.f, 0.f, 0.f};
    f32x4 t00 = __builtin_amdgcn_mfma_f32_16x16x32_f16(d0, p0, z4, 0, 0, 0);
    f32x4 t01 = __builtin_amdgcn_mfma_f32_16x16x32_f16(d0, p1, z4, 0, 0, 0);
    f32x4 t10 = __builtin_amdgcn_mfma_f32_16x16x32_f16(d1, p0, z4, 0, 0, 0);
    f32x4 t11 = __builtin_amdgcn_mfma_f32_16x16x32_f16(d1, p1, z4, 0, 0, 0);

    // C-layout -> LDS [row][col] (pad 36)
    float* S = sT[wv];
    #pragma unroll
    for (int r = 0; r < 4; ++r) {
        S[(quad * 4 + r) * TP + n]           = t00[r];
        S[(quad * 4 + r) * TP + 16 + n]      = t01[r];
        S[(16 + quad * 4 + r) * TP + n]      = t10[r];
        S[(16 + quad * 4 + r) * TP + 16 + n] = t11[r];
    }
    __syncthreads();

    // read T in A-operand layout (m = n + 16*mt, k = quad*8+j), convert fp16
    f16x8 a0, a1;
    {
        const float* rp = &S[n * TP + quad * 8];
        const float4 x0 = *(const float4*)(rp);
        const float4 x1 = *(const float4*)(rp + 4);
        const float4 x2 = *(const float4*)(rp + 16 * TP);
        const float4 x3 = *(const float4*)(rp + 16 * TP + 4);
        a0[0]=(_Float16)x0.x; a0[1]=(_Float16)x0.y; a0[2]=(_Float16)x0.z; a0[3]=(_Float16)x0.w;
        a0[4]=(_Float16)x1.x; a0[5]=(_Float16)x1.y; a0[6]=(_Float16)x1.z; a0[7]=(_Float16)x1.w;
        a1[0]=(_Float16)x2.x; a1[1]=(_Float16)x2.y; a1[2]=(_Float16)x2.z; a1[3]=(_Float16)x2.w;
        a1[4]=(_Float16)x3.x; a1[5]=(_Float16)x3.y; a1[6]=(_Float16)x3.z; a1[7]=(_Float16)x3.w;
    }

    // stage 2: Z' = T * D^T (B-frag of D^T == D fragments);  Z' = Z^T
    f32x4 q00 = __builtin_amdgcn_mfma_f32_16x16x32_f16(a0, d0, z4, 0, 0, 0);
    f32x4 q01 = __builtin_amdgcn_mfma_f32_16x16x32_f16(a0, d1, z4, 0, 0, 0);
    f32x4 q10 = __builtin_amdgcn_mfma_f32_16x16x32_f16(a1, d0, z4, 0, 0, 0);
    f32x4 q11 = __builtin_amdgcn_mfma_f32_16x16x32_f16(a1, d1, z4, 0, 0, 0);

    // grade: s = row+col (symmetric, so transpose is free);  preload 12 weights
    const int sb = quad * 4 + n;
    float W[12];
    #pragma unroll
    for (int t2 = 0; t2 < 3; ++t2)
        #pragma unroll
        for (int r = 0; r < 4; ++r) W[t2 * 4 + r] = sF[sb + 16 * t2 + r];

    float gsum = 0.f;
    #pragma unroll
    for (int r = 0; r < 4; ++r) {
        gsum = fmaf(__log2f(fabsf(q00[r]) + 1.f), W[r],     gsum);
        gsum = fmaf(__log2f(fabsf(q01[r]) + 1.f), W[4 + r], gsum);
        gsum = fmaf(__log2f(fabsf(q10[r]) + 1.f), W[4 + r], gsum);
        gsum = fmaf(__log2f(fabsf(q11[r]) + 1.f), W[8 + r], gsum);
    }
    #pragma unroll
    for (int off = 32; off > 0; off >>= 1) gsum += __shfl_down(gsum, off, 64);
    // partial for (b,l,c) -> batch b's own o=0 output chunk (2883 <= 3072)
    if (lane == 0) out[b * 3072 + l * 3 + c] = gsum;
}

// ---------------- kernel 2: fused select + gather (no workspace) ----------------
// Block b: sum 3 channel partials from out's o=0 chunk (deterministic order),
// top-2/bottom-2 via u64 key = grade_bits<<32 | idx (matches stable-argsort
// tie semantics), then overwrite this batch's 4 output chunks with the raw
// selected patches (level_y == patches: LEVEL_FILT all-ones, D orthonormal).
// All partial-reads precede the barrier; all out-writes follow it.
__global__ __launch_bounds__(256) void k_selgather(const float* __restrict__ x,
                                                   float* out) {
    __shared__ unsigned long long smx1[256], smx2[256], smn1[256], smn2[256];
    __shared__ int ssel[4];
    const int b = blockIdx.x, tid = threadIdx.x;
    unsigned long long mx1 = 0, mx2 = 0, mn1 = ~0ULL, mn2 = ~0ULL;
    for (int l = tid; l < LPB; l += 256) {
        const float* pp = out + b * 3072 + l * 3;
        float gr = pp[0] + pp[1] + pp[2];
        unsigned int bits = __float_as_uint(gr);
        unsigned long long k = ((unsigned long long)bits << 32) | (unsigned int)l;
        if (k > mx1) { mx2 = mx1; mx1 = k; } else if (k > mx2) { mx2 = k; }
        if (k < mn1) { mn2 = mn1; mn1 = k; } else if (k < mn2) { mn2 = k; }
    }
    smx1[tid] = mx1; smx2[tid] = mx2; smn1[tid] = mn1; smn2[tid] = mn2;
    for (int off = 128; off > 0; off >>= 1) {
        __syncthreads();
        if (tid < off) {
            unsigned long long a1 = smx1[tid], a2 = smx2[tid], b1 = smx1[tid + off], b2 = smx2[tid + off];
            unsigned long long lo = a1 < b1 ? a1 : b1, hi = a1 < b1 ? b1 : a1;
            unsigned long long c2 = a2 > b2 ? a2 : b2;
            smx1[tid] = hi; smx2[tid] = lo > c2 ? lo : c2;
            a1 = smn1[tid]; a2 = smn2[tid]; b1 = smn1[tid + off]; b2 = smn2[tid + off];
            lo = a1 < b1 ? a1 : b1; hi = a1 < b1 ? b1 : a1;
            c2 = a2 < b2 ? a2 : b2;
            smn1[tid] = lo; smn2[tid] = hi < c2 ? hi : c2;
        }
    }
    __syncthreads();
    if (tid == 0) {
        ssel[0] = (int)(smn1[0] & 0xffffffffu);  // x_minmin
        ssel[1] = (int)(smx1[0] & 0xffffffffu);  // x_maxmax
        ssel[2] = (int)(smn2[0] & 0xffffffffu);  // x_minmin1
        ssel[3] = (int)(smx2[0] & 0xffffffffu);  // x_maxmax1
    }
    __syncthreads();

    // gather: 4 outputs x 3 ch x 32 x 32 floats = 3072 float4 for this batch
    #pragma unroll
    for (int it = 0; it < 12; ++it) {
        const int q  = it * 256 + tid;           // [0, 3072)
        const int o  = q / 768;
        const int r2 = q - o * 768;
        const int c  = r2 >> 8;
        const int p  = r2 & 255;
        const int i  = p >> 3, j4 = p & 7;
        const int l  = ssel[o];
        const int lh = l / 31;
        const int r0 = lh * 16, c0 = (l - lh * 31) * 16;
        const float4 v = *(const float4*)(x + ((size_t)(b * 3 + c) * 512 + r0 + i) * 512 + c0 + 4 * j4);
        *(float4*)(out + (size_t)o * 49152 + b * 3072 + c * 1024 + i * 32 + 4 * j4) = v;
    }
}

extern "C" void kernel_launch(void* const* d_in, const int* in_sizes, int n_in,
                              void* d_out, int out_size, void* d_ws, size_t ws_size,
                              hipStream_t stream) {
    const float* x = (const float*)d_in[0];
    float* out     = (float*)d_out;
    (void)d_ws; (void)ws_size;                   // workspace deliberately unused
    k_grade    <<<NPC / 2, 128, 0, stream>>>(x, out);
    k_selgather<<<16,      256, 0, stream>>>(x, out);
}

// Round 4
// 102.190 us; speedup vs baseline: 1.0202x; 1.0202x over previous
//
#include <hip/hip_runtime.h>
#include <cstdint>

typedef _Float16 f16x8 __attribute__((ext_vector_type(8)));
typedef float    f32x4 __attribute__((ext_vector_type(4)));

// ---------------- compile-time DCT matrix + grade filter ----------------
constexpr double kPI  = 3.14159265358979323846264338327950288;
constexpr double kLN2 = 0.69314718055994530941723212145818;
constexpr double cos_poly(double x) {            // |x| <= pi/2, Taylor
    double x2 = x * x, term = 1.0, sum = 1.0;
    for (int n = 1; n <= 13; ++n) { term *= -x2 / double((2 * n - 1) * (2 * n)); sum += term; }
    return sum;
}
constexpr double cos_idx(int a) {                // cos(a*pi/64), a mod 128
    a &= 127;
    if (a <= 32)  return  cos_poly(a * kPI / 64.0);
    if (a <= 64)  return -cos_poly((64 - a) * kPI / 64.0);
    if (a <= 96)  return -cos_poly((a - 64) * kPI / 64.0);
    return cos_poly((128 - a) * kPI / 64.0);
}
constexpr double csqrt(double v) {
    double x = 1.0;
    for (int i = 0; i < 60; ++i) x = 0.5 * (x + v / x);
    return x;
}
// double -> float (exact constexpr cast) -> half bits, RNE, normals only.
constexpr unsigned short d2h(double dv) {
    float f = (float)dv;
    double v = (double)f;
    unsigned short s = 0;
    if (v < 0.0) { s = 0x8000; v = -v; }
    if (v == 0.0) return s;
    int e = 0;
    while (v >= 2.0) { v *= 0.5; ++e; }
    while (v < 1.0)  { v *= 2.0; --e; }
    double m = (v - 1.0) * 1024.0;               // v in [1,2)
    int mi = (int)m;
    double fr = m - (double)mi;
    if (fr > 0.5 || (fr == 0.5 && (mi & 1))) ++mi;
    int ef = e + 15;
    if (mi == 1024) { mi = 0; ++ef; }
    return (unsigned short)(s | (ef << 10) | mi);
}
// D fragments in MFMA lane order, fp16 bits, baked at compile time.
// Frag[tile][lane][j] = D[16*tile + (lane&15)][(lane>>4)*8 + j]
// (this is BOTH the A-frag of D and the B-frag of D^T — same index formula).
struct __align__(16) HTab { unsigned short h[1024]; };
constexpr HTab make_H() {
    HTab t{};
    const double s0 = csqrt(1.0 / 32.0);
    for (int tl = 0; tl < 2; ++tl)
        for (int lane = 0; lane < 64; ++lane) {
            const int m  = 16 * tl + (lane & 15);
            const int k0 = (lane >> 4) * 8;
            const double sc = (m == 0) ? s0 : 0.25;   // sqrt(2/32) == 0.25 exactly
            for (int j = 0; j < 8; ++j)
                t.h[(tl * 64 + lane) * 8 + j] = d2h(sc * cos_idx(((2 * (k0 + j) + 1) * m) & 127));
        }
    return t;
}
struct FTab { float f[64]; };
constexpr FTab make_F() {                        // f(s) = ln2 * sum_g [s in band g] 2^g/n_g
    FTab t{};                                    // ln2 folded in: kernel uses log2
    const int lo[6] = {0, 11, 22, 32, 43, 54};
    const int hi[6] = {10, 21, 32, 42, 53, 62};  // s=32 in bands 2 AND 3 (fp64 boundary = 32.0)
    const int n [6] = {66, 187, 306, 286, 165, 45};
    for (int s = 0; s < 64; ++s) {
        double acc = 0.0, w = 1.0;
        for (int g = 0; g < 6; ++g) { if (s >= lo[g] && s <= hi[g]) acc += w / double(n[g]); w *= 2.0; }
        t.f[s] = (float)(acc * kLN2);
    }
    return t;
}
__device__ constexpr HTab cH = make_H();
__device__ constexpr FTab cF = make_F();

#define NP  15376   // 16 * 961 patches (one k_grade wave per patch now)
#define LPB 961     // 31*31 patches per batch image
#define TP  36      // LDS T stride: writes bank (16q+4r+n)%32 = 2-way (free);
                    // b128 reads 16B-aligned, uniform 8-per-bank
#define CPX 1922    // blocks per XCD chunk: 15376 = 8 * 1922 (exact -> bijective)

// NO-WORKSPACE SCHEME: per-batch grades (961 floats) live inside batch b's own
// o=0 output chunk (3072 floats); k_selgather block b reads only its own chunk
// before its barrier and overwrites its own 4 chunks after.  d_ws untouched.

// ---------------- kernel 1: per-patch grade via MFMA (all 3 channels) ---------
// RESTRUCTURE (this round): one wave = one PATCH (3 channels), 64-thr blocks.
//  - 3 independent MFMA chains per wave (3x ILP for latency hiding)
//  - NO __syncthreads anywhere: all LDS is wave-private (the old 2-wave
//    barrier forced a full vmcnt/lgkmcnt drain between waves that never
//    shared data)
//  - addressing, D-frags, sF staging, W-preload, reduction, store: once per
//    patch instead of 3x
//  - channel sum folded per-lane before the tree-reduce (reassoc ~1e-7,
//    vs fp16-path deviation ~9e-3 that has passed selection 4 rounds)
// TRANSPOSE TRICK unchanged: Z' = D*P^T*D^T = Z^T; F[row+col] symmetric.
// XCD swizzle: task = (bid&7)*CPX + (bid>>3); each XCD owns 1922 consecutive
// patches = exactly 2 batch-images (L2-resident reuse window).
// Layouts (verified): A[m=lane&15][k=quad*8+j], B[k=quad*8+j][n=lane&15],
// C/D: col=lane&15, row=quad*4+reg.
__global__ __launch_bounds__(64, 2) void k_grade(const float* __restrict__ x,
                                                 float* __restrict__ out) {
    __shared__ __align__(16) float sT[3][32 * TP];
    __shared__ float sF[64];
    const int lane = threadIdx.x;                // one wave per block
    const int quad = lane >> 4, n = lane & 15;
    sF[lane] = cF.f[lane];                       // wave-private: no barrier needed

    const int bid  = blockIdx.x;                 // 15376 blocks
    const int task = (bid & 7) * CPX + (bid >> 3);
    const int b  = task / LPB, l = task - b * LPB;
    const int ph = l / 31, pw = l - ph * 31;

    // D fragments from compile-time table (L2-hot: same 2 KB for all waves)
    const f16x8* DF = (const f16x8*)cH.h;
    const f16x8 d0 = DF[lane], d1 = DF[64 + lane];

    // load P^T in B-operand layout for all 3 channels: B[quad*8+j][n] =
    // P[n][quad*8+j]; lane (quad,n) reads row ph*16+n (+16), 8 contiguous cols
    const float* pbase = x + (size_t)b * 786432
                           + (size_t)(ph * 16 + n) * 512 + pw * 16 + quad * 8;
    f16x8 p0[3], p1[3];
    #pragma unroll
    for (int c = 0; c < 3; ++c) {
        const float* pp = pbase + c * 262144;
        const float4 v0 = *(const float4*)(pp);
        const float4 v1 = *(const float4*)(pp + 4);
        const float4 v2 = *(const float4*)(pp + 16 * 512);
        const float4 v3 = *(const float4*)(pp + 16 * 512 + 4);
        p0[c][0]=(_Float16)v0.x; p0[c][1]=(_Float16)v0.y; p0[c][2]=(_Float16)v0.z; p0[c][3]=(_Float16)v0.w;
        p0[c][4]=(_Float16)v1.x; p0[c][5]=(_Float16)v1.y; p0[c][6]=(_Float16)v1.z; p0[c][7]=(_Float16)v1.w;
        p1[c][0]=(_Float16)v2.x; p1[c][1]=(_Float16)v2.y; p1[c][2]=(_Float16)v2.z; p1[c][3]=(_Float16)v2.w;
        p1[c][4]=(_Float16)v3.x; p1[c][5]=(_Float16)v3.y; p1[c][6]=(_Float16)v3.z; p1[c][7]=(_Float16)v3.w;
    }

    // stage 1 (3 channels): T_c = D * P_c^T, C-layout -> private LDS buffer
    const f32x4 z4 = {0.f, 0.f, 0.f, 0.f};
    #pragma unroll
    for (int c = 0; c < 3; ++c) {
        f32x4 t00 = __builtin_amdgcn_mfma_f32_16x16x32_f16(d0, p0[c], z4, 0, 0, 0);
        f32x4 t01 = __builtin_amdgcn_mfma_f32_16x16x32_f16(d0, p1[c], z4, 0, 0, 0);
        f32x4 t10 = __builtin_amdgcn_mfma_f32_16x16x32_f16(d1, p0[c], z4, 0, 0, 0);
        f32x4 t11 = __builtin_amdgcn_mfma_f32_16x16x32_f16(d1, p1[c], z4, 0, 0, 0);
        float* S = sT[c];
        #pragma unroll
        for (int r = 0; r < 4; ++r) {
            S[(quad * 4 + r) * TP + n]           = t00[r];
            S[(quad * 4 + r) * TP + 16 + n]      = t01[r];
            S[(16 + quad * 4 + r) * TP + n]      = t10[r];
            S[(16 + quad * 4 + r) * TP + 16 + n] = t11[r];
        }
    }
    // no barrier: same wave wrote these buffers; compiler orders via lgkmcnt

    // grade weights: s = row+col = 16*(mt+nt) + (4*quad + n) + r
    const int sb = quad * 4 + n;
    float W[12];
    #pragma unroll
    for (int t2 = 0; t2 < 3; ++t2)
        #pragma unroll
        for (int r = 0; r < 4; ++r) W[t2 * 4 + r] = sF[sb + 16 * t2 + r];

    // stage 2 (3 channels): read T in A-layout, Z'_c = T_c * D^T, accumulate
    float gsum = 0.f;
    #pragma unroll
    for (int c = 0; c < 3; ++c) {
        f16x8 a0, a1;
        const float* rp = &sT[c][n * TP + quad * 8];
        const float4 x0 = *(const float4*)(rp);
        const float4 x1 = *(const float4*)(rp + 4);
        const float4 x2 = *(const float4*)(rp + 16 * TP);
        const float4 x3 = *(const float4*)(rp + 16 * TP + 4);
        a0[0]=(_Float16)x0.x; a0[1]=(_Float16)x0.y; a0[2]=(_Float16)x0.z; a0[3]=(_Float16)x0.w;
        a0[4]=(_Float16)x1.x; a0[5]=(_Float16)x1.y; a0[6]=(_Float16)x1.z; a0[7]=(_Float16)x1.w;
        a1[0]=(_Float16)x2.x; a1[1]=(_Float16)x2.y; a1[2]=(_Float16)x2.z; a1[3]=(_Float16)x2.w;
        a1[4]=(_Float16)x3.x; a1[5]=(_Float16)x3.y; a1[6]=(_Float16)x3.z; a1[7]=(_Float16)x3.w;

        f32x4 q00 = __builtin_amdgcn_mfma_f32_16x16x32_f16(a0, d0, z4, 0, 0, 0);
        f32x4 q01 = __builtin_amdgcn_mfma_f32_16x16x32_f16(a0, d1, z4, 0, 0, 0);
        f32x4 q10 = __builtin_amdgcn_mfma_f32_16x16x32_f16(a1, d0, z4, 0, 0, 0);
        f32x4 q11 = __builtin_amdgcn_mfma_f32_16x16x32_f16(a1, d1, z4, 0, 0, 0);

        #pragma unroll
        for (int r = 0; r < 4; ++r) {
            gsum = fmaf(__log2f(fabsf(q00[r]) + 1.f), W[r],     gsum);
            gsum = fmaf(__log2f(fabsf(q01[r]) + 1.f), W[4 + r], gsum);
            gsum = fmaf(__log2f(fabsf(q10[r]) + 1.f), W[4 + r], gsum);
            gsum = fmaf(__log2f(fabsf(q11[r]) + 1.f), W[8 + r], gsum);
        }
    }
    #pragma unroll
    for (int off = 32; off > 0; off >>= 1) gsum += __shfl_down(gsum, off, 64);
    // grade for (b,l) -> batch b's own o=0 output chunk (961 <= 3072)
    if (lane == 0) out[b * 3072 + l] = gsum;
}

// ---------------- kernel 2: fused select + gather (no workspace) ----------------
// Block b: top-2/bottom-2 of its 961 grades via u64 key = grade_bits<<32 | idx
// (grades >= 0 so float-bit compare is monotonic; matches stable-argsort tie
// semantics), then overwrite this batch's 4 output chunks with the raw
// selected patches (level_y == patches: LEVEL_FILT all-ones, D orthonormal).
// All grade-reads precede the barrier; all out-writes follow it.
__global__ __launch_bounds__(256) void k_selgather(const float* __restrict__ x,
                                                   float* out) {
    __shared__ unsigned long long smx1[256], smx2[256], smn1[256], smn2[256];
    __shared__ int ssel[4];
    const int b = blockIdx.x, tid = threadIdx.x;
    unsigned long long mx1 = 0, mx2 = 0, mn1 = ~0ULL, mn2 = ~0ULL;
    for (int l = tid; l < LPB; l += 256) {
        float gr = out[b * 3072 + l];
        unsigned int bits = __float_as_uint(gr);
        unsigned long long k = ((unsigned long long)bits << 32) | (unsigned int)l;
        if (k > mx1) { mx2 = mx1; mx1 = k; } else if (k > mx2) { mx2 = k; }
        if (k < mn1) { mn2 = mn1; mn1 = k; } else if (k < mn2) { mn2 = k; }
    }
    smx1[tid] = mx1; smx2[tid] = mx2; smn1[tid] = mn1; smn2[tid] = mn2;
    for (int off = 128; off > 0; off >>= 1) {
        __syncthreads();
        if (tid < off) {
            unsigned long long a1 = smx1[tid], a2 = smx2[tid], b1 = smx1[tid + off], b2 = smx2[tid + off];
            unsigned long long lo = a1 < b1 ? a1 : b1, hi = a1 < b1 ? b1 : a1;
            unsigned long long c2 = a2 > b2 ? a2 : b2;
            smx1[tid] = hi; smx2[tid] = lo > c2 ? lo : c2;
            a1 = smn1[tid]; a2 = smn2[tid]; b1 = smn1[tid + off]; b2 = smn2[tid + off];
            lo = a1 < b1 ? a1 : b1; hi = a1 < b1 ? b1 : a1;
            c2 = a2 < b2 ? a2 : b2;
            smn1[tid] = lo; smn2[tid] = hi < c2 ? hi : c2;
        }
    }
    __syncthreads();
    if (tid == 0) {
        ssel[0] = (int)(smn1[0] & 0xffffffffu);  // x_minmin
        ssel[1] = (int)(smx1[0] & 0xffffffffu);  // x_maxmax
        ssel[2] = (int)(smn2[0] & 0xffffffffu);  // x_minmin1
        ssel[3] = (int)(smx2[0] & 0xffffffffu);  // x_maxmax1
    }
    __syncthreads();

    // gather: 4 outputs x 3 ch x 32 x 32 floats = 3072 float4 for this batch
    #pragma unroll
    for (int it = 0; it < 12; ++it) {
        const int q  = it * 256 + tid;           // [0, 3072)
        const int o  = q / 768;
        const int r2 = q - o * 768;
        const int c  = r2 >> 8;
        const int p  = r2 & 255;
        const int i  = p >> 3, j4 = p & 7;
        const int l  = ssel[o];
        const int lh = l / 31;
        const int r0 = lh * 16, c0 = (l - lh * 31) * 16;
        const float4 v = *(const float4*)(x + ((size_t)(b * 3 + c) * 512 + r0 + i) * 512 + c0 + 4 * j4);
        *(float4*)(out + (size_t)o * 49152 + b * 3072 + c * 1024 + i * 32 + 4 * j4) = v;
    }
}

extern "C" void kernel_launch(void* const* d_in, const int* in_sizes, int n_in,
                              void* d_out, int out_size, void* d_ws, size_t ws_size,
                              hipStream_t stream) {
    const float* x = (const float*)d_in[0];
    float* out     = (float*)d_out;
    (void)d_ws; (void)ws_size;                   // workspace deliberately unused
    k_grade    <<<NP, 64, 0, stream>>>(x, out);
    k_selgather<<<16, 256, 0, stream>>>(x, out);
}